// Round 12
// baseline (233.808 us; speedup 1.0000x reference)
//
#include <hip/hip_runtime.h>
#include <math.h>

// B=8, C=64, H=512, W=512, K=8, HID=64, nh=nw=64, L=4096
//
//  A) mlp_precompute: pk[L][64], pb[L] into d_ws (runs once, ~8 us).
//  B) afpm_main (R12) = R8 (best, 226.4 us) + bijective XCD swizzle.
//     Theory: WRITE inflation (1.58x) comes from the 4 tile-blocks of the
//     same (b,ph) band -- which write 4 x 512B islands of the same 2KB
//     plane-rows -- landing on 4 different XCDs (tile was the fastest grid
//     dim, dispatch round-robins XCDs). Remap: 1D grid, bid%8 = XCD gets a
//     contiguous 256-block chunk of original ids -> the 4 tiles of each
//     band are consecutive on ONE XCD, so their sectors merge in that L2
//     before writeback. Everything else identical to R8.

static __device__ __forceinline__ float gelu_erf(float x) {
    return 0.5f * x * (1.0f + erff(x * 0.70710678118654752f));
}

__global__ __launch_bounds__(256) void mlp_precompute(
    const float* __restrict__ w1k, const float* __restrict__ b1k,
    const float* __restrict__ w2k, const float* __restrict__ b2k,
    const float* __restrict__ w1b, const float* __restrict__ b1b,
    const float* __restrict__ w2b, const float* __restrict__ b2b,
    float* __restrict__ pk_out,   // [L][64]
    float* __restrict__ pb_out)   // [L]
{
    constexpr int HID = 64;
    const int tid = threadIdx.x;
    const int pi  = tid >> 6;
    const int j   = tid & 63;
    const int l   = blockIdx.x * 4 + pi;

    const int py_i = l >> 6;
    const int px_i = l & 63;
    const float py = (float)(py_i * 8) + 4.0f - 256.0f;
    const float px = (float)(px_i * 8) + 4.0f - 256.0f;
    const float dd = sqrtf(py * py + px * px) * (1.0f / 362.03867196751236f);

    __shared__ float gk[4][HID];
    __shared__ float gb[4][HID];

    gk[pi][j] = gelu_erf(dd * w1k[j] + b1k[j]);
    gb[pi][j] = gelu_erf(dd * w1b[j] + b1b[j]);
    __syncthreads();

    float s = b2k[j];
#pragma unroll 8
    for (int h = 0; h < HID; ++h)
        s += gk[pi][h] * w2k[h * HID + j];
    pk_out[l * HID + j] = s;

    if (j == 0) {
        float t = b2b[0];
        for (int h = 0; h < HID; ++h)
            t += gb[pi][h] * w2b[h];
        pb_out[l] = t;
    }
}

__global__ __launch_bounds__(1024, 4) void afpm_main(
    const float* __restrict__ x,
    const float* __restrict__ conv_w, const float* __restrict__ conv_b,
    const float* __restrict__ pk_g,   // [L][64]
    const float* __restrict__ pb_g,   // [L]
    float* __restrict__ out)
{
    constexpr int W = 512;

    const int tid  = threadIdx.x;
    const int u    = tid & 15;         // 0..15: 4-col slice within each half
    const int c    = tid >> 4;         // 0..63 channel

    // ---- bijective XCD swizzle: nwg=2048, 8 XCDs, 256 blocks/XCD chunk ----
    // xcd = bid % 8 (dispatch round-robin); orig = xcd*256 + bid/8.
    // orig decomposes tile-fastest: (tile:4, ph:64, b:8) -> the 4 tiles of
    // each (b,ph) band are consecutive orig on the same XCD.
    const int bid  = blockIdx.x;
    const int orig = (bid & 7) * 256 + (bid >> 3);
    const int tile = orig & 3;         // 0..3 : 128-col tile
    const int ph   = (orig >> 2) & 63; // 0..63
    const int b    = orig >> 8;        // 0..7

    __shared__ float pkL[16][68];      // 16 patches x 64 kernel elems (pad 68)
    __shared__ float f0T[16][68];      // [patch][cc], pad 68
    __shared__ float pbL[16];

    const int lbase = ph * 64 + tile * 16;   // first global patch of tile

    // ---- pixel loads: 16 float4; wave covers 4 planes x 512B per instr-pair
    const size_t base = (((size_t)b * 64 + c) * 512 + (size_t)ph * 8) * (size_t)W
                        + (size_t)(tile * 128);
    const float* xp0 = x + base + 4 * u;        // half0: cols [4u..4u+3]
    const float* xp1 = x + base + 64 + 4 * u;   // half1: +64
    float4 v0[8], v1[8];
#pragma unroll
    for (int r = 0; r < 8; ++r) {
        v0[r] = *(const float4*)(xp0 + r * W);
        v1[r] = *(const float4*)(xp1 + r * W);
    }

    // ---- stage pk (1024 floats = 1/thread) and pb ----
    pkL[tid >> 6][tid & 63] = pk_g[(size_t)lbase * 64 + tid];
    if (tid < 16) pbL[tid] = pb_g[lbase + tid];
    __syncthreads();                       // barrier 1

    // ---- per-thread partial dots for the two patches ----
    const int p0 = u >> 1;                 // patch in half0 (0..7)
    const int p1 = 8 + (u >> 1);           // patch in half1 (8..15)
    const int co = (u & 1) * 4;            // col offset within patch
    float s0 = 0.0f, s1 = 0.0f;
#pragma unroll
    for (int r = 0; r < 8; ++r) {
        const int k0 = r * 8 + co;
        const float4 a = v0[r];
        s0 += a.x * pkL[p0][k0 + 0] + a.y * pkL[p0][k0 + 1]
            + a.z * pkL[p0][k0 + 2] + a.w * pkL[p0][k0 + 3];
        const float4 d = v1[r];
        s1 += d.x * pkL[p1][k0 + 0] + d.y * pkL[p1][k0 + 1]
            + d.z * pkL[p1][k0 + 2] + d.w * pkL[p1][k0 + 3];
    }
    s0 += __shfl_xor(s0, 1);               // combine 4-col halves of patch
    s1 += __shfl_xor(s1, 1);
    if ((u & 1) == 0) f0T[p0][c] = s0 + pbL[p0];
    else              f0T[p1][c] = s1 + pbL[p1];
    __syncthreads();                       // barrier 2

    // ---- conv: thread (c,u) computes modulator for (o=c, patch=u) ----
    float t = 0.0f;
    const float4* cw = (const float4*)(conv_w + (size_t)c * 64);
#pragma unroll
    for (int i = 0; i < 16; ++i) {
        const float4 w = cw[i];
        const float4 f = *(const float4*)&f0T[u][i * 4];
        t += w.x * f.x + w.y * f.y + w.z * f.z + w.w * f.w;
    }
    const float m_self = t + conv_b[c];

    // fetch this thread's two modulators from the in-wave 16-lane c-group
    const int lane  = tid & 63;
    const int laneC = lane & 48;           // first lane of this c-group
    const float m0 = __shfl(m_self, laneC + p0);
    const float m1 = __shfl(m_self, laneC + p1);

    // ---- modulate + store (same span pattern as loads) ----
    float* op0 = out + base + 4 * u;
    float* op1 = out + base + 64 + 4 * u;
#pragma unroll
    for (int r = 0; r < 8; ++r) {
        float4 a = v0[r];
        a.x *= m0; a.y *= m0; a.z *= m0; a.w *= m0;
        *(float4*)(op0 + r * W) = a;
        float4 d = v1[r];
        d.x *= m1; d.y *= m1; d.z *= m1; d.w *= m1;
        *(float4*)(op1 + r * W) = d;
    }
}

extern "C" void kernel_launch(void* const* d_in, const int* in_sizes, int n_in,
                              void* d_out, int out_size, void* d_ws, size_t ws_size,
                              hipStream_t stream) {
    const float* x      = (const float*)d_in[0];
    const float* w1k    = (const float*)d_in[1];
    const float* b1k    = (const float*)d_in[2];
    const float* w2k    = (const float*)d_in[3];
    const float* b2k    = (const float*)d_in[4];
    const float* w1b    = (const float*)d_in[5];
    const float* b1b    = (const float*)d_in[6];
    const float* w2b    = (const float*)d_in[7];
    const float* b2b    = (const float*)d_in[8];
    const float* conv_w = (const float*)d_in[9];
    const float* conv_b = (const float*)d_in[10];
    float* out = (float*)d_out;

    constexpr int L = 64 * 64;
    float* pk = (float*)d_ws;            // L*64 floats = 1 MiB
    float* pb = pk + (size_t)L * 64;     // L floats

    mlp_precompute<<<L / 4, 256, 0, stream>>>(w1k, b1k, w2k, b2k,
                                              w1b, b1b, w2b, b2b, pk, pb);

    // 2048 blocks, 1D; (tile, ph, b) derived via bijective XCD swizzle
    afpm_main<<<2048, 1024, 0, stream>>>(x, conv_w, conv_b, pk, pb, out);
}